// Round 1
// baseline (355.118 us; speedup 1.0000x reference)
//
#include <hip/hip_runtime.h>

// GraphConv scatter-add: out[tidx[e], :] += inputs[sidx[e], :] * (esgn[e]*enorm[e])
// N=100000 nodes, E=1600000 edges, D=64 feature dims (fp32).
//
// Mapping: one 64-lane wave per edge; lane = feature dim.
// Block 256 = 4 edges/block. Per-edge scalars (sidx, tidx, w) are loaded by
// all lanes at the same address -> hardware broadcast, no shuffle needed.
// Gather read is 64 contiguous floats (256 B) -> fully coalesced.
// Scatter is 64 contiguous float atomicAdds -> coalesced atomic traffic to L2.

#define D_FEAT 64
#define EDGES_PER_BLOCK 4

__global__ void graphconv_scatter(const float* __restrict__ inputs,
                                  const int* __restrict__ eidx,
                                  const float* __restrict__ enorm,
                                  const float* __restrict__ esgn,
                                  float* __restrict__ out,
                                  int n_edges) {
    int e = blockIdx.x * EDGES_PER_BLOCK + (threadIdx.x >> 6);
    if (e >= n_edges) return;
    int lane = threadIdx.x & 63;

    int s = eidx[e];            // source node  (eidx row 0)
    int t = eidx[n_edges + e];  // target node  (eidx row 1)
    float w = esgn[e] * enorm[e];

    float val = inputs[s * D_FEAT + lane] * w;
    atomicAdd(&out[t * D_FEAT + lane], val);
}

extern "C" void kernel_launch(void* const* d_in, const int* in_sizes, int n_in,
                              void* d_out, int out_size, void* d_ws, size_t ws_size,
                              hipStream_t stream) {
    const float* inputs = (const float*)d_in[0];
    const int*   eidx   = (const int*)d_in[1];
    const float* enorm  = (const float*)d_in[2];
    const float* esgn   = (const float*)d_in[3];
    float* out = (float*)d_out;

    const int n_edges = in_sizes[2];  // enorm element count = E

    // Output is accumulated with atomics -> must start from zero every call
    // (harness poisons d_out once and does not re-poison between replays).
    hipMemsetAsync(d_out, 0, (size_t)out_size * sizeof(float), stream);

    int blocks = (n_edges + EDGES_PER_BLOCK - 1) / EDGES_PER_BLOCK;
    graphconv_scatter<<<blocks, 256, 0, stream>>>(inputs, eidx, enorm, esgn,
                                                  out, n_edges);
}

// Round 2
// 259.618 us; speedup vs baseline: 1.3678x; 1.3678x over previous
//
#include <hip/hip_runtime.h>

// GraphConv scatter-add via on-the-fly CSR (counting sort by target):
//   out[t,:] = sum_{e: tidx[e]=t} inputs[sidx[e],:] * (esgn[e]*enorm[e])
// N=100000, E=1600000, D=64 fp32.
//
// Baseline (1 atomicAdd per output dword) was pinned at L2 atomic-op rate
// (102.4M atomics / 352us ~= 291 G/s ~= channel limit). Here feature data is
// accumulated in registers; only the 4-B sort bookkeeping uses atomics
// (2 x 1.6M ops, 64x fewer).

#define DF 64
#define THREADS 256

// ---- phase 1: count edges per target node --------------------------------
__global__ void k_count(const int* __restrict__ tidx, int* __restrict__ cnt, int E) {
    int i = blockIdx.x * blockDim.x + threadIdx.x;
    if (i < E) atomicAdd(&cnt[tidx[i]], 1);
}

// ---- phase 2: exclusive scan of cnt -> offs (3 small kernels) -------------
__global__ void k_scan_block(const int* __restrict__ cnt, int* __restrict__ offs,
                             int* __restrict__ partial, int N) {
    __shared__ int sh[1024];
    int t = threadIdx.x;
    int idx = blockIdx.x * 1024 + t;
    sh[t] = (idx < N) ? cnt[idx] : 0;
    __syncthreads();
    // Hillis-Steele inclusive scan over the block
    for (int off = 1; off < 1024; off <<= 1) {
        int v = (t >= off) ? sh[t - off] : 0;
        __syncthreads();
        sh[t] += v;
        __syncthreads();
    }
    if (idx < N) offs[idx + 1] = sh[t];          // block-local inclusive
    if (t == 1023) partial[blockIdx.x] = sh[1023];
}

__global__ void k_scan_partial(int* partial, int nb) {
    __shared__ int sh[1024];
    int t = threadIdx.x;
    if (t < nb) sh[t] = partial[t];
    __syncthreads();
    if (t == 0) {                 // nb ~= 98: serial LDS scan is ~free
        int run = 0;
        for (int i = 0; i < nb; ++i) { int v = sh[i]; sh[i] = run; run += v; }
    }
    __syncthreads();
    if (t < nb) partial[t] = sh[t];               // now exclusive block offsets
}

__global__ void k_scan_final(const int* __restrict__ cnt, int* __restrict__ offs,
                             const int* __restrict__ partial,
                             int* __restrict__ cursor, int N) {
    int idx = blockIdx.x * blockDim.x + threadIdx.x;
    if (idx < N) {
        int v = offs[idx + 1] + partial[idx >> 10];  // scanA block = 1024 elems
        offs[idx + 1] = v;                           // global inclusive
        cursor[idx] = v - cnt[idx];                  // = exclusive start
        if (idx == 0) offs[0] = 0;
    }
}

// ---- phase 3: scatter (sidx, w) records into CSR order --------------------
__global__ void k_scatter(const int* __restrict__ eidx, const float* __restrict__ enorm,
                          const float* __restrict__ esgn, int* __restrict__ cursor,
                          int2* __restrict__ rec, int E) {
    int i = blockIdx.x * blockDim.x + threadIdx.x;
    if (i >= E) return;
    int s = eidx[i];
    int t = eidx[E + i];
    float w = esgn[i] * enorm[i];
    int pos = atomicAdd(&cursor[t], 1);
    rec[pos] = make_int2(s, __float_as_int(w));
}

// ---- phase 4: per-node segment sum, no atomics ----------------------------
// One wave per node. 4 edge-slots (lane>>4) x 16 lanes x float4 (lane&15):
// each slot walks every 4th edge of the segment, so 4 independent gather
// chains are in flight; final cross-slot reduce via shfl_xor(16|32).
__global__ void k_accum(const float4* __restrict__ in4, const int* __restrict__ offs,
                        const int2* __restrict__ rec, float4* __restrict__ out4, int N) {
    int node = blockIdx.x * (THREADS / 64) + (threadIdx.x >> 6);
    if (node >= N) return;
    int lane = threadIdx.x & 63;
    int g = lane >> 4;     // edge slot 0..3
    int c = lane & 15;     // float4 column 0..15

    int beg = offs[node], end = offs[node + 1];
    float4 acc = make_float4(0.f, 0.f, 0.f, 0.f);
    for (int j = beg + g; j < end; j += 4) {
        int2 r = rec[j];
        float w = __int_as_float(r.y);
        float4 v = in4[(size_t)r.x * 16 + c];
        acc.x += v.x * w;
        acc.y += v.y * w;
        acc.z += v.z * w;
        acc.w += v.w * w;
    }
    // combine the 4 slots
    acc.x += __shfl_xor(acc.x, 16); acc.y += __shfl_xor(acc.y, 16);
    acc.z += __shfl_xor(acc.z, 16); acc.w += __shfl_xor(acc.w, 16);
    acc.x += __shfl_xor(acc.x, 32); acc.y += __shfl_xor(acc.y, 32);
    acc.z += __shfl_xor(acc.z, 32); acc.w += __shfl_xor(acc.w, 32);
    if (lane < 16) out4[(size_t)node * 16 + c] = acc;  // covers all nodes -> no memset(out)
}

// ---- fallback (ws too small): original atomic kernel ----------------------
__global__ void k_atomic(const float* __restrict__ inputs, const int* __restrict__ eidx,
                         const float* __restrict__ enorm, const float* __restrict__ esgn,
                         float* __restrict__ out, int E) {
    int e = blockIdx.x * 4 + (threadIdx.x >> 6);
    if (e >= E) return;
    int lane = threadIdx.x & 63;
    int s = eidx[e];
    int t = eidx[E + e];
    float w = esgn[e] * enorm[e];
    atomicAdd(&out[t * DF + lane], inputs[s * DF + lane] * w);
}

extern "C" void kernel_launch(void* const* d_in, const int* in_sizes, int n_in,
                              void* d_out, int out_size, void* d_ws, size_t ws_size,
                              hipStream_t stream) {
    const float* inputs = (const float*)d_in[0];
    const int*   eidx   = (const int*)d_in[1];
    const float* enorm  = (const float*)d_in[2];
    const float* esgn   = (const float*)d_in[3];
    float* out = (float*)d_out;

    const int E = in_sizes[2];       // enorm count
    const int N = out_size / DF;     // nodes

    // workspace layout
    char* ws = (char*)d_ws;
    int* cnt     = (int*)ws;                       // N
    int* offs    = cnt + N;                        // N+1
    int* partial = offs + N + 1;                   // <=1024
    int* cursor  = partial + 1024;                 // N
    size_t rec_off = ((size_t)((char*)(cursor + N) - ws) + 15) & ~(size_t)15;
    int2* rec = (int2*)(ws + rec_off);             // E records, 8 B each
    size_t needed = rec_off + (size_t)E * sizeof(int2);

    if (ws_size < needed) {
        hipMemsetAsync(d_out, 0, (size_t)out_size * sizeof(float), stream);
        k_atomic<<<(E + 3) / 4, 256, 0, stream>>>(inputs, eidx, enorm, esgn, out, E);
        return;
    }

    hipMemsetAsync(cnt, 0, (size_t)N * sizeof(int), stream);

    int nbA = (N + 1023) / 1024;
    k_count     <<<(E + THREADS - 1) / THREADS, THREADS, 0, stream>>>(eidx + E, cnt, E);
    k_scan_block<<<nbA, 1024, 0, stream>>>(cnt, offs, partial, N);
    k_scan_partial<<<1, 1024, 0, stream>>>(partial, nbA);
    k_scan_final<<<(N + THREADS - 1) / THREADS, THREADS, 0, stream>>>(cnt, offs, partial, cursor, N);
    k_scatter   <<<(E + THREADS - 1) / THREADS, THREADS, 0, stream>>>(eidx, enorm, esgn, cursor, rec, E);
    k_accum     <<<(N + 3) / 4, THREADS, 0, stream>>>((const float4*)inputs, offs, rec,
                                                      (float4*)out, N);
}